// Round 5
// baseline (228.242 us; speedup 1.0000x reference)
//
#include <hip/hip_runtime.h>

#define H 1024
#define HH (H * H)
#define BATCH 8192
#define NSTEPS 50

typedef __attribute__((ext_vector_type(8))) short bf16x8;
typedef __attribute__((ext_vector_type(4))) float f32x4;

// ---------------------------------------------------------------------------
// helpers
// ---------------------------------------------------------------------------
__device__ __forceinline__ void split2(float a, unsigned short& h, unsigned short& l)
{
    unsigned u = __float_as_uint(a);
    float r = a - __uint_as_float(u & 0xFFFF0000u);   // exact residual
    h = (unsigned short)(u >> 16);                    // truncated bf16
    l = (unsigned short)((__float_as_uint(r) + 0x8000u) >> 16); // rounded residual
}
__device__ __forceinline__ float bf2f(unsigned short s)
{
    return __uint_as_float(((unsigned)s) << 16);
}
__device__ __forceinline__ void gload16(const void* g, void* l)
{
    __builtin_amdgcn_global_load_lds(
        (const __attribute__((address_space(1))) void*)g,
        (__attribute__((address_space(3))) void*)l, 16, 0, 0);
}
#define VMCNT(n) asm volatile("s_waitcnt vmcnt(" #n ")" ::: "memory")
#define RBAR() do { __builtin_amdgcn_s_barrier(); __builtin_amdgcn_sched_barrier(0); } while (0)

// ---------------------------------------------------------------------------
// build A = I + h*W as bf16 hi/lo planes; c = h*b (fp32, also v0)
// ---------------------------------------------------------------------------
__global__ void build_k(unsigned short* __restrict__ Ahi, unsigned short* __restrict__ Alo,
                        const float* __restrict__ W,
                        const float* __restrict__ t0, const float* __restrict__ t1)
{
    const float h = (t1[0] - t0[0]) / (float)NSTEPS;
    const int i4 = blockIdx.x * 256 + threadIdx.x;   // float4 index
    const int idx = i4 * 4;
    const int r = idx >> 10;
    const int cb = idx & 1023;
    const float4 w = ((const float4*)W)[i4];
    float a[4] = {h * w.x, h * w.y, h * w.z, h * w.w};
    #pragma unroll
    for (int j = 0; j < 4; ++j)
        if (cb + j == r) a[j] += 1.0f;
    ushort4 hv, lv;
    split2(a[0], hv.x, lv.x);
    split2(a[1], hv.y, lv.y);
    split2(a[2], hv.z, lv.z);
    split2(a[3], hv.w, lv.w);
    ((ushort4*)Ahi)[i4] = hv;
    ((ushort4*)Alo)[i4] = lv;
}

__global__ void build_c_k(float* __restrict__ cvec, float* __restrict__ v0,
                          const float* __restrict__ b,
                          const float* __restrict__ t0, const float* __restrict__ t1)
{
    const float h = (t1[0] - t0[0]) / (float)NSTEPS;
    const int i = blockIdx.x * 256 + threadIdx.x;
    const float v = h * b[i];
    cvec[i] = v;
    v0[i] = v;
}

// ---------------------------------------------------------------------------
// transpose a pair of bf16 planes (1024x1024): D = S^T
// ---------------------------------------------------------------------------
__global__ void transpose_pair_k(const unsigned short* __restrict__ Shi,
                                 const unsigned short* __restrict__ Slo,
                                 unsigned short* __restrict__ Dhi,
                                 unsigned short* __restrict__ Dlo)
{
    __shared__ unsigned short th[64][68], tl[64][68];
    const int t = threadIdx.x;
    const int cb = blockIdx.x * 64;  // src col base
    const int rb = blockIdx.y * 64;  // src row base
    #pragma unroll
    for (int p = 0; p < 4; ++p) {
        const int row = p * 16 + (t >> 4);
        const int c4 = (t & 15) * 4;
        *(ushort4*)&th[row][c4] = *(const ushort4*)&Shi[(size_t)(rb + row) * H + cb + c4];
        *(ushort4*)&tl[row][c4] = *(const ushort4*)&Slo[(size_t)(rb + row) * H + cb + c4];
    }
    __syncthreads();
    #pragma unroll
    for (int p = 0; p < 4; ++p) {
        const int row = p * 16 + (t >> 4);      // dst row = src col
        const int c4 = (t & 15) * 4;            // dst col = src row
        ushort4 hv, lv;
        hv.x = th[c4 + 0][row]; hv.y = th[c4 + 1][row];
        hv.z = th[c4 + 2][row]; hv.w = th[c4 + 3][row];
        lv.x = tl[c4 + 0][row]; lv.y = tl[c4 + 1][row];
        lv.z = tl[c4 + 2][row]; lv.w = tl[c4 + 3][row];
        *(ushort4*)&Dhi[(size_t)(cb + row) * H + rb + c4] = hv;
        *(ushort4*)&Dlo[(size_t)(cb + row) * H + rb + c4] = lv;
    }
}

// ---------------------------------------------------------------------------
// fused chain step: 272 blocks x 512 threads.
//  blocks [0,256):  Q = L * R, 64x64 tile, 8 waves in-block split-K=2,
//                   3-product split-2 bf16 MFMA, 3-buffer counted-vmcnt pipe
//  blocks [256,272): vout = addv + (Lhi+Llo) * vin
// ---------------------------------------------------------------------------
template<bool WRITE_T>
__launch_bounds__(512)
__global__ void chain_fused_k(const unsigned short* __restrict__ Lhi,
                              const unsigned short* __restrict__ Llo,
                              const unsigned short* __restrict__ RThi,
                              const unsigned short* __restrict__ RTlo,
                              unsigned short* __restrict__ Qhi,
                              unsigned short* __restrict__ Qlo,
                              unsigned short* __restrict__ QhiT,
                              unsigned short* __restrict__ QloT,
                              const float* __restrict__ vin,
                              const float* __restrict__ addv,
                              float* __restrict__ vout)
{
    __shared__ unsigned short sA[3][2][2][64][32];  // [buf][khalf][plane][row][k] 48KB
    __shared__ unsigned short sB[3][2][2][64][32];  // 48KB

    const int tid = threadIdx.x;
    const int bid = blockIdx.x;
    const int wave = tid >> 6, lane = tid & 63;

    if (bid >= 256) {
        // ---- matvec blocks ----
        const int rowbase = (bid - 256) * 64 + wave * 8;
        const float4* xq = (const float4*)vin + lane * 4;
        float4 xv[4];
        #pragma unroll
        for (int q = 0; q < 4; ++q) xv[q] = xq[q];
        #pragma unroll
        for (int rr = 0; rr < 8; ++rr) {
            const int row = rowbase + rr;
            const unsigned short* mh = Lhi + (size_t)row * H + lane * 16;
            const unsigned short* ml = Llo + (size_t)row * H + lane * 16;
            bf16x8 h0 = *(const bf16x8*)&mh[0];
            bf16x8 h1 = *(const bf16x8*)&mh[8];
            bf16x8 l0 = *(const bf16x8*)&ml[0];
            bf16x8 l1 = *(const bf16x8*)&ml[8];
            float s = 0.0f;
            #pragma unroll
            for (int q = 0; q < 8; ++q) {
                const float m0v = bf2f((unsigned short)h0[q]) + bf2f((unsigned short)l0[q]);
                const float m1v = bf2f((unsigned short)h1[q]) + bf2f((unsigned short)l1[q]);
                const float* xf = (const float*)xv;
                s = fmaf(m0v, xf[q], s);
                s = fmaf(m1v, xf[8 + q], s);
            }
            #pragma unroll
            for (int off = 32; off; off >>= 1)
                s += __shfl_down(s, off, 64);
            if (lane == 0) vout[row] = addv[row] + s;
        }
        return;
    }

    // ---- GEMM blocks ----
    const int lg = lane >> 4, lm = lane & 15;
    const int half = wave >> 2;               // k-half owner
    const int wq = wave & 3;
    const int wr2 = (wq >> 1) * 32, wc2 = (wq & 1) * 32;
    const int swz = (bid & 7) * 32 + (bid >> 3);
    const int m0 = (swz >> 4) * 64, n0 = (swz & 15) * 64;

    f32x4 acc[2][2] = {};

    // stage one 32-wide k-step of both k-halves: 32KB, 4 gload16/thread
    #define CSTAGE(tt, b) do {                                                   \
        _Pragma("unroll")                                                        \
        for (int it = 0; it < 4; ++it) {                                         \
            const int idx = tid + it * 512;                                      \
            const int mat = idx >> 10, kh = (idx >> 9) & 1;                      \
            const int plane = (idx >> 8) & 1;                                    \
            const int row = (idx >> 2) & 63, kc = idx & 3;                       \
            const int ks = kc ^ ((row >> 1) & 3);                                \
            const unsigned short* g = mat ? (plane ? RTlo : RThi)                \
                                          : (plane ? Llo : Lhi);                 \
            const int rb = mat ? n0 : m0;                                        \
            unsigned short* d = mat ? &sB[b][kh][plane][row][kc * 8]             \
                                    : &sA[b][kh][plane][row][kc * 8];            \
            gload16(g + (size_t)(rb + row) * H + kh * 512 + (tt) * 32 + ks * 8, d); \
        }                                                                        \
    } while (0)

    CSTAGE(0, 0);
    CSTAGE(1, 1);
    VMCNT(4);
    RBAR();

    #pragma unroll
    for (int t = 0; t < 16; ++t) {
        const int b = t % 3;
        bf16x8 ah[2], al[2], bh[2], bl[2];
        #pragma unroll
        for (int i = 0; i < 2; ++i) {
            const int row = wr2 + i * 16 + lm;
            const int sl = lg ^ ((row >> 1) & 3);
            ah[i] = *(const bf16x8*)&sA[b][half][0][row][sl * 8];
            al[i] = *(const bf16x8*)&sA[b][half][1][row][sl * 8];
            const int rn = wc2 + i * 16 + lm;
            const int sn = lg ^ ((rn >> 1) & 3);
            bh[i] = *(const bf16x8*)&sB[b][half][0][rn][sn * 8];
            bl[i] = *(const bf16x8*)&sB[b][half][1][rn][sn * 8];
        }
        if (t + 2 < 16) CSTAGE(t + 2, (t + 2) % 3);
        __builtin_amdgcn_s_setprio(1);
        #pragma unroll
        for (int i = 0; i < 2; ++i)
            #pragma unroll
            for (int j = 0; j < 2; ++j) {
                acc[i][j] = __builtin_amdgcn_mfma_f32_16x16x32_bf16(ah[i], bh[j], acc[i][j], 0, 0, 0);
                acc[i][j] = __builtin_amdgcn_mfma_f32_16x16x32_bf16(ah[i], bl[j], acc[i][j], 0, 0, 0);
                acc[i][j] = __builtin_amdgcn_mfma_f32_16x16x32_bf16(al[i], bh[j], acc[i][j], 0, 0, 0);
            }
        __builtin_amdgcn_s_setprio(0);
        if (t < 14) VMCNT(4);
        else if (t == 14) VMCNT(0);
        RBAR();
    }
    #undef CSTAGE

    // cross-half reduce via LDS (stride 17 floats)
    float* red = (float*)&sA[0][0][0][0][0];
    const int ridx = wq * 64 + lane;
    if (half == 1) {
        float* dst = red + (size_t)ridx * 17;
        #pragma unroll
        for (int i = 0; i < 2; ++i)
            #pragma unroll
            for (int j = 0; j < 2; ++j)
                *(f32x4*)&dst[(i * 2 + j) * 4] = acc[i][j];
    }
    __syncthreads();
    if (half == 0) {
        const float* src = red + (size_t)ridx * 17;
        #pragma unroll
        for (int i = 0; i < 2; ++i)
            #pragma unroll
            for (int j = 0; j < 2; ++j) {
                const f32x4 p = *(const f32x4*)&src[(i * 2 + j) * 4];
                acc[i][j] += p;
            }
        #pragma unroll
        for (int i = 0; i < 2; ++i) {
            const int row0 = m0 + wr2 + i * 16 + lg * 4;
            #pragma unroll
            for (int j = 0; j < 2; ++j) {
                const int col = n0 + wc2 + j * 16 + lm;
                unsigned short hs[4], ls[4];
                #pragma unroll
                for (int r = 0; r < 4; ++r) {
                    split2(acc[i][j][r], hs[r], ls[r]);
                    Qhi[(size_t)(row0 + r) * H + col] = hs[r];
                    Qlo[(size_t)(row0 + r) * H + col] = ls[r];
                }
                if (WRITE_T) {
                    ushort4 th, tl;
                    th.x = hs[0]; th.y = hs[1]; th.z = hs[2]; th.w = hs[3];
                    tl.x = ls[0]; tl.y = ls[1]; tl.z = ls[2]; tl.w = ls[3];
                    *(ushort4*)&QhiT[(size_t)col * H + row0] = th;
                    *(ushort4*)&QloT[(size_t)col * H + row0] = tl;
                }
            }
        }
    }
}

// ---------------------------------------------------------------------------
// X [1024][8192] fp32 -> transposed bf16 planes XT [8192][1024] (hi/lo)
// ---------------------------------------------------------------------------
__global__ void transpose_split_X_k(const float* __restrict__ X,
                                    unsigned short* __restrict__ XhiT,
                                    unsigned short* __restrict__ XloT)
{
    __shared__ float ts[64][65];
    const int t = threadIdx.x;
    const int n0 = blockIdx.x * 64;   // batch base
    const int k0 = blockIdx.y * 64;   // k base
    #pragma unroll
    for (int p = 0; p < 4; ++p) {
        const int row = p * 16 + (t >> 4);       // k-local
        const int c4 = (t & 15) * 4;             // n-local
        const float4 v = *(const float4*)&X[(size_t)(k0 + row) * BATCH + n0 + c4];
        ts[row][c4 + 0] = v.x; ts[row][c4 + 1] = v.y;
        ts[row][c4 + 2] = v.z; ts[row][c4 + 3] = v.w;
    }
    __syncthreads();
    #pragma unroll
    for (int p = 0; p < 2; ++p) {
        const int n = p * 32 + (t >> 3);         // n-local
        const int kc = (t & 7) * 8;              // k-local chunk
        bf16x8 hv, lv;
        #pragma unroll
        for (int q = 0; q < 8; ++q) {
            unsigned short hh, ll;
            split2(ts[kc + q][n], hh, ll);
            hv[q] = (short)hh;
            lv[q] = (short)ll;
        }
        *(bf16x8*)&XhiT[(size_t)(n0 + n) * H + k0 + kc] = hv;
        *(bf16x8*)&XloT[(size_t)(n0 + n) * H + k0 + kc] = lv;
    }
}

// ---------------------------------------------------------------------------
// big GEMM, pipelined: C = P * X + bias. 128x128 tile, 8 waves (32x64 each),
// BK=32, 3-buffer counted-vmcnt pipe, all operands pre-split bf16 planes.
// ---------------------------------------------------------------------------
__launch_bounds__(512)
__global__ void big_gemm_pipe_k(const unsigned short* __restrict__ Phi,
                                const unsigned short* __restrict__ Plo,
                                const unsigned short* __restrict__ XhiT,
                                const unsigned short* __restrict__ XloT,
                                float* __restrict__ C, const float* __restrict__ bias)
{
    __shared__ unsigned short sA[3][2][128][32];   // [buf][plane][row][k] 48KB
    __shared__ unsigned short sB[3][2][128][32];   // 48KB

    const int tid = threadIdx.x;
    const int wave = tid >> 6, lane = tid & 63;
    const int lg = lane >> 4, lm = lane & 15;
    const int wr2 = (wave & 3) * 32;     // m offset of wave tile (32 rows)
    const int wc2 = (wave >> 2) * 64;    // n offset of wave tile (64 cols)
    const int bid = blockIdx.x;
    const int swz = (bid & 7) * 64 + (bid >> 3);   // XCD swizzle (512 % 8 == 0)
    const int m0 = (swz >> 6) * 128, n0 = (swz & 63) * 128;

    f32x4 acc[2][4] = {};

    #define BSTAGE(tt, b) do {                                                   \
        _Pragma("unroll")                                                        \
        for (int it = 0; it < 4; ++it) {                                         \
            const int idx = tid + it * 512;                                      \
            const int mat = idx >> 10, plane = (idx >> 9) & 1;                   \
            const int row = (idx >> 2) & 127, kc = idx & 3;                      \
            const int ks = kc ^ ((row >> 1) & 3);                                \
            const unsigned short* g = mat ? (plane ? XloT : XhiT)                \
                                          : (plane ? Plo : Phi);                 \
            const int rb = mat ? n0 : m0;                                        \
            unsigned short* d = mat ? &sB[b][plane][row][kc * 8]                 \
                                    : &sA[b][plane][row][kc * 8];                \
            gload16(g + (size_t)(rb + row) * H + (tt) * 32 + ks * 8, d);         \
        }                                                                        \
    } while (0)

    BSTAGE(0, 0);
    BSTAGE(1, 1);
    VMCNT(4);
    RBAR();

    #pragma unroll
    for (int t = 0; t < 32; ++t) {
        const int b = t % 3;
        bf16x8 ah[2], al[2], bh[4], bl[4];
        #pragma unroll
        for (int i = 0; i < 2; ++i) {
            const int row = wr2 + i * 16 + lm;
            const int sl = lg ^ ((row >> 1) & 3);
            ah[i] = *(const bf16x8*)&sA[b][0][row][sl * 8];
            al[i] = *(const bf16x8*)&sA[b][1][row][sl * 8];
        }
        #pragma unroll
        for (int j = 0; j < 4; ++j) {
            const int rn = wc2 + j * 16 + lm;
            const int sn = lg ^ ((rn >> 1) & 3);
            bh[j] = *(const bf16x8*)&sB[b][0][rn][sn * 8];
            bl[j] = *(const bf16x8*)&sB[b][1][rn][sn * 8];
        }
        if (t + 2 < 32) BSTAGE(t + 2, (t + 2) % 3);
        __builtin_amdgcn_s_setprio(1);
        #pragma unroll
        for (int i = 0; i < 2; ++i)
            #pragma unroll
            for (int j = 0; j < 4; ++j) {
                acc[i][j] = __builtin_amdgcn_mfma_f32_16x16x32_bf16(ah[i], bh[j], acc[i][j], 0, 0, 0);
                acc[i][j] = __builtin_amdgcn_mfma_f32_16x16x32_bf16(ah[i], bl[j], acc[i][j], 0, 0, 0);
                acc[i][j] = __builtin_amdgcn_mfma_f32_16x16x32_bf16(al[i], bh[j], acc[i][j], 0, 0, 0);
            }
        __builtin_amdgcn_s_setprio(0);
        if (t < 30) VMCNT(4);
        else if (t == 30) VMCNT(0);
        if (t < 31) RBAR();
    }
    #undef BSTAGE

    #pragma unroll
    for (int i = 0; i < 2; ++i) {
        const int row0 = m0 + wr2 + i * 16 + lg * 4;
        #pragma unroll
        for (int r = 0; r < 4; ++r) {
            const float bv = bias[row0 + r];
            float* dst = &C[(size_t)(row0 + r) * BATCH + n0 + wc2 + lm];
            #pragma unroll
            for (int j = 0; j < 4; ++j)
                dst[j * 16] = acc[i][j][r] + bv;
        }
    }
}

// ---------------------------------------------------------------------------
// big GEMM fallback (X split in-kernel) — known-good ~70us path
// ---------------------------------------------------------------------------
#define PADK 40

__launch_bounds__(256)
__global__ void big_gemm_k(const unsigned short* __restrict__ Ahi_g,
                           const unsigned short* __restrict__ Alo_g,
                           const float* __restrict__ X, float* __restrict__ C,
                           const float* __restrict__ bias)
{
    __shared__ unsigned short Ahi[128][PADK], Alo[128][PADK];
    __shared__ unsigned short Bhi[128][PADK], Blo[128][PADK];

    const int tid = threadIdx.x;
    const int wave = tid >> 6;
    const int lane = tid & 63;
    const int wr = (wave >> 1) * 64;
    const int wc = (wave & 1) * 64;
    const int m0 = blockIdx.y * 128;
    const int n0 = blockIdx.x * 128;
    const int lg = lane >> 4;
    const int lm = lane & 15;

    f32x4 acc[4][4] = {};

    for (int k0 = 0; k0 < H; k0 += 32) {
        #pragma unroll
        for (int a2 = 0; a2 < 2; ++a2) {
            const int id = tid + a2 * 256;
            const int row = id >> 2;
            const int ko = id & 3;
            const size_t g = (size_t)(m0 + row) * H + k0 + ko * 8;
            *(bf16x8*)&Ahi[row][ko * 8] = *(const bf16x8*)&Ahi_g[g];
            *(bf16x8*)&Alo[row][ko * 8] = *(const bf16x8*)&Alo_g[g];
        }
        #pragma unroll
        for (int a2 = 0; a2 < 2; ++a2) {
            const int id = tid + a2 * 256;
            const int n = id & 127;
            const int ko = id >> 7;
            const float* src = &X[(size_t)(k0 + ko * 8) * BATCH + n0 + n];
            bf16x8 bh, bl;
            #pragma unroll
            for (int i = 0; i < 8; ++i) {
                unsigned short hh, ll;
                split2(src[(size_t)i * BATCH], hh, ll);
                bh[i] = (short)hh;
                bl[i] = (short)ll;
            }
            *(bf16x8*)&Bhi[n][ko * 8] = bh;
            *(bf16x8*)&Blo[n][ko * 8] = bl;
        }
        __syncthreads();

        bf16x8 ah[4], al[4], bh[4], bl[4];
        #pragma unroll
        for (int i = 0; i < 4; ++i) {
            const int m = wr + i * 16 + lm;
            ah[i] = *(const bf16x8*)&Ahi[m][lg * 8];
            al[i] = *(const bf16x8*)&Alo[m][lg * 8];
            const int n = wc + i * 16 + lm;
            bh[i] = *(const bf16x8*)&Bhi[n][lg * 8];
            bl[i] = *(const bf16x8*)&Blo[n][lg * 8];
        }
        #pragma unroll
        for (int i = 0; i < 4; ++i)
            #pragma unroll
            for (int j = 0; j < 4; ++j) {
                acc[i][j] = __builtin_amdgcn_mfma_f32_16x16x32_bf16(ah[i], bh[j], acc[i][j], 0, 0, 0);
                acc[i][j] = __builtin_amdgcn_mfma_f32_16x16x32_bf16(ah[i], bl[j], acc[i][j], 0, 0, 0);
                acc[i][j] = __builtin_amdgcn_mfma_f32_16x16x32_bf16(al[i], bh[j], acc[i][j], 0, 0, 0);
            }
        __syncthreads();
    }

    #pragma unroll
    for (int i = 0; i < 4; ++i) {
        const int rowb = m0 + wr + i * 16 + lg * 4;
        #pragma unroll
        for (int r = 0; r < 4; ++r) {
            const float bv = bias[rowb + r];
            float* dst = &C[(size_t)(rowb + r) * BATCH + n0 + wc + lm];
            #pragma unroll
            for (int j = 0; j < 4; ++j)
                dst[j * 16] = acc[i][j][r] + bv;
        }
    }
}

// ---------------------------------------------------------------------------
// host-side launcher
// ---------------------------------------------------------------------------
extern "C" void kernel_launch(void* const* d_in, const int* in_sizes, int n_in,
                              void* d_out, int out_size, void* d_ws, size_t ws_size,
                              hipStream_t stream)
{
    const float* x0 = (const float*)d_in[0];
    const float* t0 = (const float*)d_in[1];
    const float* t1 = (const float*)d_in[2];
    const float* W  = (const float*)d_in[3];
    const float* bb = (const float*)d_in[4];
    float* out = (float*)d_out;

    // ws layout: A planes {hi,lo,hiT,loT} (8MB) | cv,v0,v1 | @16MB: XT planes (32MB)
    unsigned short* Ahi  = (unsigned short*)d_ws;
    unsigned short* Alo  = Ahi + HH;
    unsigned short* AhiT = Alo + HH;
    unsigned short* AloT = AhiT + HH;
    float* cv = (float*)(AloT + HH);
    float* v0 = cv + H;
    float* v1 = v0 + H;

    const size_t xtoff = (size_t)16 * 1024 * 1024;
    const bool useXT = ws_size >= xtoff + (size_t)2 * BATCH * H * sizeof(unsigned short);
    unsigned short* XhiT = (unsigned short*)((char*)d_ws + xtoff);
    unsigned short* XloT = XhiT + (size_t)BATCH * H;

    // d_out scratch: two ping-pong plane-sets {hi,lo,hiT,loT}, 8MB each (16MB),
    // fully overwritten by the final 32MB C write.
    unsigned short* PA = (unsigned short*)d_out;
    unsigned short* PB = PA + (size_t)4 * HH;

    build_k<<<HH / 1024, 256, 0, stream>>>(Ahi, Alo, W, t0, t1);
    build_c_k<<<H / 256, 256, 0, stream>>>(cv, v0, bb, t0, t1);
    transpose_pair_k<<<dim3(16, 16), 256, 0, stream>>>(Ahi, Alo, AhiT, AloT);

    // addition chain 1 -> 2 -> 3 -> 6 -> 12 -> 24 -> 25 -> 50
    const int seq[7] = {0, 1, 0, 0, 0, 1, 0};   // 0=SQ, 1=MUL
    unsigned short* cur = Ahi;                  // P_1 = A (4 consecutive planes)
    float* vin = v0;
    float* vout = v1;
    for (int s = 0; s < 7; ++s) {
        const unsigned short* L  = seq[s] ? Ahi : cur;
        const unsigned short* Ll = seq[s] ? Alo : cur + HH;
        const float* addv = seq[s] ? cv : vin;
        if (s < 6) {
            unsigned short* nxt = (s & 1) ? PB : PA;
            chain_fused_k<true><<<272, 512, 0, stream>>>(
                L, Ll, cur + 2 * HH, cur + 3 * HH,
                nxt, nxt + HH, nxt + 2 * HH, nxt + 3 * HH,
                vin, addv, vout);
            cur = nxt;
        } else {
            chain_fused_k<false><<<272, 512, 0, stream>>>(
                L, Ll, cur + 2 * HH, cur + 3 * HH,
                Ahi, Alo, nullptr, nullptr,
                vin, addv, vout);
            cur = Ahi;
        }
        float* tv = vin; vin = vout; vout = tv;
    }
    // cur = P_50 planes (in ws); vin = v_50

    if (useXT) {
        transpose_split_X_k<<<dim3(BATCH / 64, H / 64), 256, 0, stream>>>(x0, XhiT, XloT);
        big_gemm_pipe_k<<<512, 512, 0, stream>>>(Ahi, Alo, XhiT, XloT, out, vin);
    } else {
        big_gemm_k<<<dim3(BATCH / 128, H / 128), 256, 0, stream>>>(
            Ahi, Alo, x0, out, vin);
    }
}

// Round 6
// 192.475 us; speedup vs baseline: 1.1858x; 1.1858x over previous
//
#include <hip/hip_runtime.h>

#define H 1024
#define HH (H * H)
#define BATCH 8192
#define NSTEPS 50

typedef __attribute__((ext_vector_type(8))) short bf16x8;
typedef __attribute__((ext_vector_type(4))) float f32x4;

// ---------------------------------------------------------------------------
// helpers
// ---------------------------------------------------------------------------
__device__ __forceinline__ void split2(float a, unsigned short& h, unsigned short& l)
{
    unsigned u = __float_as_uint(a);
    float r = a - __uint_as_float(u & 0xFFFF0000u);   // exact residual
    h = (unsigned short)(u >> 16);                    // truncated bf16
    l = (unsigned short)((__float_as_uint(r) + 0x8000u) >> 16); // rounded residual
}
__device__ __forceinline__ float bf2f(unsigned short s)
{
    return __uint_as_float(((unsigned)s) << 16);
}
__device__ __forceinline__ void gload16(const void* g, void* l)
{
    __builtin_amdgcn_global_load_lds(
        (const __attribute__((address_space(1))) void*)g,
        (__attribute__((address_space(3))) void*)l, 16, 0, 0);
}
#define VMCNT(n) asm volatile("s_waitcnt vmcnt(" #n ")" ::: "memory")
#define RBAR() do { __builtin_amdgcn_s_barrier(); __builtin_amdgcn_sched_barrier(0); } while (0)

// ---------------------------------------------------------------------------
// build A = I + h*W as bf16 hi/lo planes; c = h*b (fp32, also v0)
// ---------------------------------------------------------------------------
__global__ void build_k(unsigned short* __restrict__ Ahi, unsigned short* __restrict__ Alo,
                        const float* __restrict__ W,
                        const float* __restrict__ t0, const float* __restrict__ t1)
{
    const float h = (t1[0] - t0[0]) / (float)NSTEPS;
    const int i4 = blockIdx.x * 256 + threadIdx.x;   // float4 index
    const int idx = i4 * 4;
    const int r = idx >> 10;
    const int cb = idx & 1023;
    const float4 w = ((const float4*)W)[i4];
    float a[4] = {h * w.x, h * w.y, h * w.z, h * w.w};
    #pragma unroll
    for (int j = 0; j < 4; ++j)
        if (cb + j == r) a[j] += 1.0f;
    ushort4 hv, lv;
    split2(a[0], hv.x, lv.x);
    split2(a[1], hv.y, lv.y);
    split2(a[2], hv.z, lv.z);
    split2(a[3], hv.w, lv.w);
    ((ushort4*)Ahi)[i4] = hv;
    ((ushort4*)Alo)[i4] = lv;
}

__global__ void build_c_k(float* __restrict__ cvec, float* __restrict__ v0,
                          const float* __restrict__ b,
                          const float* __restrict__ t0, const float* __restrict__ t1)
{
    const float h = (t1[0] - t0[0]) / (float)NSTEPS;
    const int i = blockIdx.x * 256 + threadIdx.x;
    const float v = h * b[i];
    cvec[i] = v;
    v0[i] = v;
}

// ---------------------------------------------------------------------------
// transpose a pair of bf16 planes (1024x1024): D = S^T
// ---------------------------------------------------------------------------
__global__ void transpose_pair_k(const unsigned short* __restrict__ Shi,
                                 const unsigned short* __restrict__ Slo,
                                 unsigned short* __restrict__ Dhi,
                                 unsigned short* __restrict__ Dlo)
{
    __shared__ unsigned short th[64][68], tl[64][68];
    const int t = threadIdx.x;
    const int cb = blockIdx.x * 64;  // src col base
    const int rb = blockIdx.y * 64;  // src row base
    #pragma unroll
    for (int p = 0; p < 4; ++p) {
        const int row = p * 16 + (t >> 4);
        const int c4 = (t & 15) * 4;
        *(ushort4*)&th[row][c4] = *(const ushort4*)&Shi[(size_t)(rb + row) * H + cb + c4];
        *(ushort4*)&tl[row][c4] = *(const ushort4*)&Slo[(size_t)(rb + row) * H + cb + c4];
    }
    __syncthreads();
    #pragma unroll
    for (int p = 0; p < 4; ++p) {
        const int row = p * 16 + (t >> 4);      // dst row = src col
        const int c4 = (t & 15) * 4;            // dst col = src row
        ushort4 hv, lv;
        hv.x = th[c4 + 0][row]; hv.y = th[c4 + 1][row];
        hv.z = th[c4 + 2][row]; hv.w = th[c4 + 3][row];
        lv.x = tl[c4 + 0][row]; lv.y = tl[c4 + 1][row];
        lv.z = tl[c4 + 2][row]; lv.w = tl[c4 + 3][row];
        *(ushort4*)&Dhi[(size_t)(cb + row) * H + rb + c4] = hv;
        *(ushort4*)&Dlo[(size_t)(cb + row) * H + rb + c4] = lv;
    }
}

// ---------------------------------------------------------------------------
// fused chain step (round-4 structure, 3-product MFMA): 272 blocks x 512 thr.
//  blocks [0,256):  Q = L * R  (64x64 tile, 8 waves, in-block split-K=2,
//                   2-buffer __syncthreads staging via gload_lds)
//  blocks [256,272): vout = addv + (Lhi+Llo) * vin
// ---------------------------------------------------------------------------
template<bool WRITE_T>
__launch_bounds__(512)
__global__ void chain_fused_k(const unsigned short* __restrict__ Lhi,
                              const unsigned short* __restrict__ Llo,
                              const unsigned short* __restrict__ RThi,
                              const unsigned short* __restrict__ RTlo,
                              unsigned short* __restrict__ Qhi,
                              unsigned short* __restrict__ Qlo,
                              unsigned short* __restrict__ QhiT,
                              unsigned short* __restrict__ QloT,
                              const float* __restrict__ vin,
                              const float* __restrict__ addv,
                              float* __restrict__ vout)
{
    __shared__ unsigned short sA[2][2][2][64][32];  // [dbuf][khalf][plane][row][k] 32KB
    __shared__ unsigned short sB[2][2][2][64][32];  // 32KB

    const int tid = threadIdx.x;
    const int bid = blockIdx.x;
    const int wave = tid >> 6, lane = tid & 63;

    if (bid >= 256) {
        // ---- matvec blocks ----
        const int rowbase = (bid - 256) * 64 + wave * 8;
        const float4* xq = (const float4*)vin + lane * 4;
        float4 xv[4];
        #pragma unroll
        for (int q = 0; q < 4; ++q) xv[q] = xq[q];
        #pragma unroll
        for (int rr = 0; rr < 8; ++rr) {
            const int row = rowbase + rr;
            const unsigned short* mh = Lhi + (size_t)row * H + lane * 16;
            const unsigned short* ml = Llo + (size_t)row * H + lane * 16;
            bf16x8 h0 = *(const bf16x8*)&mh[0];
            bf16x8 h1 = *(const bf16x8*)&mh[8];
            bf16x8 l0 = *(const bf16x8*)&ml[0];
            bf16x8 l1 = *(const bf16x8*)&ml[8];
            float s = 0.0f;
            #pragma unroll
            for (int q = 0; q < 8; ++q) {
                const float m0v = bf2f((unsigned short)h0[q]) + bf2f((unsigned short)l0[q]);
                const float m1v = bf2f((unsigned short)h1[q]) + bf2f((unsigned short)l1[q]);
                const float* xf = (const float*)xv;
                s = fmaf(m0v, xf[q], s);
                s = fmaf(m1v, xf[8 + q], s);
            }
            #pragma unroll
            for (int off = 32; off; off >>= 1)
                s += __shfl_down(s, off, 64);
            if (lane == 0) vout[row] = addv[row] + s;
        }
        return;
    }

    // ---- GEMM blocks ----
    const int lg = lane >> 4, lm = lane & 15;
    const int half = wave >> 2;               // k-half owner
    const int wq = wave & 3;
    const int wr2 = (wq >> 1) * 32, wc2 = (wq & 1) * 32;
    const int swz = (bid & 7) * 32 + (bid >> 3);
    const int m0 = (swz >> 4) * 64, n0 = (swz & 15) * 64;

    f32x4 acc[2][2] = {};

    #define CSTAGE(tt, b) do {                                                   \
        _Pragma("unroll")                                                        \
        for (int it = 0; it < 4; ++it) {                                         \
            const int idx = tid + it * 512;                                      \
            const int mat = idx >> 10, kh = (idx >> 9) & 1;                      \
            const int plane = (idx >> 8) & 1;                                    \
            const int row = (idx >> 2) & 63, kc = idx & 3;                       \
            const int ks = kc ^ ((row >> 1) & 3);                                \
            const unsigned short* g = mat ? (plane ? RTlo : RThi)                \
                                          : (plane ? Llo : Lhi);                 \
            const int rb = mat ? n0 : m0;                                        \
            unsigned short* d = mat ? &sB[b][kh][plane][row][kc * 8]             \
                                    : &sA[b][kh][plane][row][kc * 8];            \
            gload16(g + (size_t)(rb + row) * H + kh * 512 + (tt) * 32 + ks * 8, d); \
        }                                                                        \
    } while (0)

    CSTAGE(0, 0);
    __syncthreads();
    int buf = 0;
    for (int t = 0; t < 16; ++t) {
        if (t + 1 < 16) CSTAGE(t + 1, buf ^ 1);
        bf16x8 ah[2], al[2], bh[2], bl[2];
        #pragma unroll
        for (int i = 0; i < 2; ++i) {
            const int row = wr2 + i * 16 + lm;
            const int sl = lg ^ ((row >> 1) & 3);
            ah[i] = *(const bf16x8*)&sA[buf][half][0][row][sl * 8];
            al[i] = *(const bf16x8*)&sA[buf][half][1][row][sl * 8];
            const int rn = wc2 + i * 16 + lm;
            const int sn = lg ^ ((rn >> 1) & 3);
            bh[i] = *(const bf16x8*)&sB[buf][half][0][rn][sn * 8];
            bl[i] = *(const bf16x8*)&sB[buf][half][1][rn][sn * 8];
        }
        #pragma unroll
        for (int i = 0; i < 2; ++i)
            #pragma unroll
            for (int j = 0; j < 2; ++j) {
                acc[i][j] = __builtin_amdgcn_mfma_f32_16x16x32_bf16(ah[i], bh[j], acc[i][j], 0, 0, 0);
                acc[i][j] = __builtin_amdgcn_mfma_f32_16x16x32_bf16(ah[i], bl[j], acc[i][j], 0, 0, 0);
                acc[i][j] = __builtin_amdgcn_mfma_f32_16x16x32_bf16(al[i], bh[j], acc[i][j], 0, 0, 0);
            }
        __syncthreads();
        buf ^= 1;
    }
    #undef CSTAGE

    // cross-half reduce via LDS (stride 17 floats)
    float* red = (float*)&sA[0][0][0][0][0];
    const int ridx = wq * 64 + lane;
    if (half == 1) {
        float* dst = red + (size_t)ridx * 17;
        #pragma unroll
        for (int i = 0; i < 2; ++i)
            #pragma unroll
            for (int j = 0; j < 2; ++j)
                *(f32x4*)&dst[(i * 2 + j) * 4] = acc[i][j];
    }
    __syncthreads();
    if (half == 0) {
        const float* src = red + (size_t)ridx * 17;
        #pragma unroll
        for (int i = 0; i < 2; ++i)
            #pragma unroll
            for (int j = 0; j < 2; ++j) {
                const f32x4 p = *(const f32x4*)&src[(i * 2 + j) * 4];
                acc[i][j] += p;
            }
        #pragma unroll
        for (int i = 0; i < 2; ++i) {
            const int row0 = m0 + wr2 + i * 16 + lg * 4;
            #pragma unroll
            for (int j = 0; j < 2; ++j) {
                const int col = n0 + wc2 + j * 16 + lm;
                unsigned short hs[4], ls[4];
                #pragma unroll
                for (int r = 0; r < 4; ++r) {
                    split2(acc[i][j][r], hs[r], ls[r]);
                    Qhi[(size_t)(row0 + r) * H + col] = hs[r];
                    Qlo[(size_t)(row0 + r) * H + col] = ls[r];
                }
                if (WRITE_T) {
                    ushort4 th, tl;
                    th.x = hs[0]; th.y = hs[1]; th.z = hs[2]; th.w = hs[3];
                    tl.x = ls[0]; tl.y = ls[1]; tl.z = ls[2]; tl.w = ls[3];
                    *(ushort4*)&QhiT[(size_t)col * H + row0] = th;
                    *(ushort4*)&QloT[(size_t)col * H + row0] = tl;
                }
            }
        }
    }
}

// ---------------------------------------------------------------------------
// X [1024][8192] fp32 -> transposed bf16 planes XT [8192][1024] (hi/lo)
// ---------------------------------------------------------------------------
__global__ void transpose_split_X_k(const float* __restrict__ X,
                                    unsigned short* __restrict__ XhiT,
                                    unsigned short* __restrict__ XloT)
{
    __shared__ float ts[64][65];
    const int t = threadIdx.x;
    const int n0 = blockIdx.x * 64;   // batch base
    const int k0 = blockIdx.y * 64;   // k base
    #pragma unroll
    for (int p = 0; p < 4; ++p) {
        const int row = p * 16 + (t >> 4);       // k-local
        const int c4 = (t & 15) * 4;             // n-local
        const float4 v = *(const float4*)&X[(size_t)(k0 + row) * BATCH + n0 + c4];
        ts[row][c4 + 0] = v.x; ts[row][c4 + 1] = v.y;
        ts[row][c4 + 2] = v.z; ts[row][c4 + 3] = v.w;
    }
    __syncthreads();
    #pragma unroll
    for (int p = 0; p < 2; ++p) {
        const int n = p * 32 + (t >> 3);         // n-local
        const int kc = (t & 7) * 8;              // k-local chunk
        bf16x8 hv, lv;
        #pragma unroll
        for (int q = 0; q < 8; ++q) {
            unsigned short hh, ll;
            split2(ts[kc + q][n], hh, ll);
            hv[q] = (short)hh;
            lv[q] = (short)ll;
        }
        *(bf16x8*)&XhiT[(size_t)(n0 + n) * H + k0 + kc] = hv;
        *(bf16x8*)&XloT[(size_t)(n0 + n) * H + k0 + kc] = lv;
    }
}

// ---------------------------------------------------------------------------
// big GEMM, pipelined: C = P * X + bias. 128x128 tile, 8 waves (32x64 each),
// BK=32, 3-buffer counted-vmcnt pipe, all operands pre-split bf16 planes.
// XCD swizzle: n-slice per XCD (XT slice 4MB = L2-resident), m-inner order.
// ---------------------------------------------------------------------------
__launch_bounds__(512)
__global__ void big_gemm_pipe_k(const unsigned short* __restrict__ Phi,
                                const unsigned short* __restrict__ Plo,
                                const unsigned short* __restrict__ XhiT,
                                const unsigned short* __restrict__ XloT,
                                float* __restrict__ C, const float* __restrict__ bias)
{
    __shared__ unsigned short sA[3][2][128][32];   // [buf][plane][row][k] 48KB
    __shared__ unsigned short sB[3][2][128][32];   // 48KB

    const int tid = threadIdx.x;
    const int wave = tid >> 6, lane = tid & 63;
    const int lg = lane >> 4, lm = lane & 15;
    const int wr2 = (wave & 3) * 32;     // m offset of wave tile (32 rows)
    const int wc2 = (wave >> 2) * 64;    // n offset of wave tile (64 cols)
    const int bid = blockIdx.x;
    // XCD x (bid&7) owns n-tiles [8x, 8x+8); m varies fastest within the XCD.
    const int l = bid >> 3;
    const int m0 = (l & 7) * 128;
    const int n0 = ((bid & 7) * 8 + (l >> 3)) * 128;

    f32x4 acc[2][4] = {};

    #define BSTAGE(tt, b) do {                                                   \
        _Pragma("unroll")                                                        \
        for (int it = 0; it < 4; ++it) {                                         \
            const int idx = tid + it * 512;                                      \
            const int mat = idx >> 10, plane = (idx >> 9) & 1;                   \
            const int row = (idx >> 2) & 127, kc = idx & 3;                      \
            const int ks = kc ^ ((row >> 1) & 3);                                \
            const unsigned short* g = mat ? (plane ? XloT : XhiT)                \
                                          : (plane ? Plo : Phi);                 \
            const int rb = mat ? n0 : m0;                                        \
            unsigned short* d = mat ? &sB[b][plane][row][kc * 8]                 \
                                    : &sA[b][plane][row][kc * 8];                \
            gload16(g + (size_t)(rb + row) * H + (tt) * 32 + ks * 8, d);         \
        }                                                                        \
    } while (0)

    BSTAGE(0, 0);
    BSTAGE(1, 1);
    VMCNT(4);
    RBAR();

    #pragma unroll
    for (int t = 0; t < 32; ++t) {
        const int b = t % 3;
        bf16x8 ah[2], al[2], bh[4], bl[4];
        #pragma unroll
        for (int i = 0; i < 2; ++i) {
            const int row = wr2 + i * 16 + lm;
            const int sl = lg ^ ((row >> 1) & 3);
            ah[i] = *(const bf16x8*)&sA[b][0][row][sl * 8];
            al[i] = *(const bf16x8*)&sA[b][1][row][sl * 8];
        }
        #pragma unroll
        for (int j = 0; j < 4; ++j) {
            const int rn = wc2 + j * 16 + lm;
            const int sn = lg ^ ((rn >> 1) & 3);
            bh[j] = *(const bf16x8*)&sB[b][0][rn][sn * 8];
            bl[j] = *(const bf16x8*)&sB[b][1][rn][sn * 8];
        }
        if (t + 2 < 32) BSTAGE(t + 2, (t + 2) % 3);
        __builtin_amdgcn_s_setprio(1);
        #pragma unroll
        for (int i = 0; i < 2; ++i)
            #pragma unroll
            for (int j = 0; j < 4; ++j) {
                acc[i][j] = __builtin_amdgcn_mfma_f32_16x16x32_bf16(ah[i], bh[j], acc[i][j], 0, 0, 0);
                acc[i][j] = __builtin_amdgcn_mfma_f32_16x16x32_bf16(ah[i], bl[j], acc[i][j], 0, 0, 0);
                acc[i][j] = __builtin_amdgcn_mfma_f32_16x16x32_bf16(al[i], bh[j], acc[i][j], 0, 0, 0);
            }
        __builtin_amdgcn_s_setprio(0);
        if (t < 30) VMCNT(4);
        else if (t == 30) VMCNT(0);
        if (t < 31) RBAR();
    }
    #undef BSTAGE

    #pragma unroll
    for (int i = 0; i < 2; ++i) {
        const int row0 = m0 + wr2 + i * 16 + lg * 4;
        #pragma unroll
        for (int r = 0; r < 4; ++r) {
            const float bv = bias[row0 + r];
            float* dst = &C[(size_t)(row0 + r) * BATCH + n0 + wc2 + lm];
            #pragma unroll
            for (int j = 0; j < 4; ++j)
                dst[j * 16] = acc[i][j][r] + bv;
        }
    }
}

// ---------------------------------------------------------------------------
// big GEMM fallback (X split in-kernel) — known-good ~70us path
// ---------------------------------------------------------------------------
#define PADK 40

__launch_bounds__(256)
__global__ void big_gemm_k(const unsigned short* __restrict__ Ahi_g,
                           const unsigned short* __restrict__ Alo_g,
                           const float* __restrict__ X, float* __restrict__ C,
                           const float* __restrict__ bias)
{
    __shared__ unsigned short Ahi[128][PADK], Alo[128][PADK];
    __shared__ unsigned short Bhi[128][PADK], Blo[128][PADK];

    const int tid = threadIdx.x;
    const int wave = tid >> 6;
    const int lane = tid & 63;
    const int wr = (wave >> 1) * 64;
    const int wc = (wave & 1) * 64;
    const int m0 = blockIdx.y * 128;
    const int n0 = blockIdx.x * 128;
    const int lg = lane >> 4;
    const int lm = lane & 15;

    f32x4 acc[4][4] = {};

    for (int k0 = 0; k0 < H; k0 += 32) {
        #pragma unroll
        for (int a2 = 0; a2 < 2; ++a2) {
            const int id = tid + a2 * 256;
            const int row = id >> 2;
            const int ko = id & 3;
            const size_t g = (size_t)(m0 + row) * H + k0 + ko * 8;
            *(bf16x8*)&Ahi[row][ko * 8] = *(const bf16x8*)&Ahi_g[g];
            *(bf16x8*)&Alo[row][ko * 8] = *(const bf16x8*)&Alo_g[g];
        }
        #pragma unroll
        for (int a2 = 0; a2 < 2; ++a2) {
            const int id = tid + a2 * 256;
            const int n = id & 127;
            const int ko = id >> 7;
            const float* src = &X[(size_t)(k0 + ko * 8) * BATCH + n0 + n];
            bf16x8 bh, bl;
            #pragma unroll
            for (int i = 0; i < 8; ++i) {
                unsigned short hh, ll;
                split2(src[(size_t)i * BATCH], hh, ll);
                bh[i] = (short)hh;
                bl[i] = (short)ll;
            }
            *(bf16x8*)&Bhi[n][ko * 8] = bh;
            *(bf16x8*)&Blo[n][ko * 8] = bl;
        }
        __syncthreads();

        bf16x8 ah[4], al[4], bh[4], bl[4];
        #pragma unroll
        for (int i = 0; i < 4; ++i) {
            const int m = wr + i * 16 + lm;
            ah[i] = *(const bf16x8*)&Ahi[m][lg * 8];
            al[i] = *(const bf16x8*)&Alo[m][lg * 8];
            const int n = wc + i * 16 + lm;
            bh[i] = *(const bf16x8*)&Bhi[n][lg * 8];
            bl[i] = *(const bf16x8*)&Blo[n][lg * 8];
        }
        #pragma unroll
        for (int i = 0; i < 4; ++i)
            #pragma unroll
            for (int j = 0; j < 4; ++j) {
                acc[i][j] = __builtin_amdgcn_mfma_f32_16x16x32_bf16(ah[i], bh[j], acc[i][j], 0, 0, 0);
                acc[i][j] = __builtin_amdgcn_mfma_f32_16x16x32_bf16(ah[i], bl[j], acc[i][j], 0, 0, 0);
                acc[i][j] = __builtin_amdgcn_mfma_f32_16x16x32_bf16(al[i], bh[j], acc[i][j], 0, 0, 0);
            }
        __syncthreads();
    }

    #pragma unroll
    for (int i = 0; i < 4; ++i) {
        const int rowb = m0 + wr + i * 16 + lg * 4;
        #pragma unroll
        for (int r = 0; r < 4; ++r) {
            const float bv = bias[rowb + r];
            float* dst = &C[(size_t)(rowb + r) * BATCH + n0 + wc + lm];
            #pragma unroll
            for (int j = 0; j < 4; ++j)
                dst[j * 16] = acc[i][j][r] + bv;
        }
    }
}

// ---------------------------------------------------------------------------
// host-side launcher
// ---------------------------------------------------------------------------
extern "C" void kernel_launch(void* const* d_in, const int* in_sizes, int n_in,
                              void* d_out, int out_size, void* d_ws, size_t ws_size,
                              hipStream_t stream)
{
    const float* x0 = (const float*)d_in[0];
    const float* t0 = (const float*)d_in[1];
    const float* t1 = (const float*)d_in[2];
    const float* W  = (const float*)d_in[3];
    const float* bb = (const float*)d_in[4];
    float* out = (float*)d_out;

    // ws layout: A planes {hi,lo,hiT,loT} (8MB) | cv,v0,v1 | @16MB: XT planes (32MB)
    unsigned short* Ahi  = (unsigned short*)d_ws;
    unsigned short* Alo  = Ahi + HH;
    unsigned short* AhiT = Alo + HH;
    unsigned short* AloT = AhiT + HH;
    float* cv = (float*)(AloT + HH);
    float* v0 = cv + H;
    float* v1 = v0 + H;

    const size_t xtoff = (size_t)16 * 1024 * 1024;
    const bool useXT = ws_size >= xtoff + (size_t)2 * BATCH * H * sizeof(unsigned short);
    unsigned short* XhiT = (unsigned short*)((char*)d_ws + xtoff);
    unsigned short* XloT = XhiT + (size_t)BATCH * H;

    // d_out scratch: two ping-pong plane-sets {hi,lo,hiT,loT}, 8MB each (16MB),
    // fully overwritten by the final 32MB C write.
    unsigned short* PA = (unsigned short*)d_out;
    unsigned short* PB = PA + (size_t)4 * HH;

    build_k<<<HH / 1024, 256, 0, stream>>>(Ahi, Alo, W, t0, t1);
    build_c_k<<<H / 256, 256, 0, stream>>>(cv, v0, bb, t0, t1);
    transpose_pair_k<<<dim3(16, 16), 256, 0, stream>>>(Ahi, Alo, AhiT, AloT);

    // addition chain 1 -> 2 -> 3 -> 6 -> 12 -> 24 -> 25 -> 50
    const int seq[7] = {0, 1, 0, 0, 0, 1, 0};   // 0=SQ, 1=MUL
    unsigned short* cur = Ahi;                  // P_1 = A (4 consecutive planes)
    float* vin = v0;
    float* vout = v1;
    for (int s = 0; s < 7; ++s) {
        const unsigned short* L  = seq[s] ? Ahi : cur;
        const unsigned short* Ll = seq[s] ? Alo : cur + HH;
        const float* addv = seq[s] ? cv : vin;
        if (s < 6) {
            unsigned short* nxt = (s & 1) ? PB : PA;
            chain_fused_k<true><<<272, 512, 0, stream>>>(
                L, Ll, cur + 2 * HH, cur + 3 * HH,
                nxt, nxt + HH, nxt + 2 * HH, nxt + 3 * HH,
                vin, addv, vout);
            cur = nxt;
        } else {
            chain_fused_k<false><<<272, 512, 0, stream>>>(
                L, Ll, cur + 2 * HH, cur + 3 * HH,
                Ahi, Alo, nullptr, nullptr,
                vin, addv, vout);
            cur = Ahi;
        }
        float* tv = vin; vin = vout; vout = tv;
    }
    // cur = P_50 planes (in ws); vin = v_50

    if (useXT) {
        transpose_split_X_k<<<dim3(BATCH / 64, H / 64), 256, 0, stream>>>(x0, XhiT, XloT);
        big_gemm_pipe_k<<<512, 512, 0, stream>>>(Ahi, Alo, XhiT, XloT, out, vin);
    } else {
        big_gemm_k<<<dim3(BATCH / 128, H / 128), 256, 0, stream>>>(
            Ahi, Alo, x0, out, vin);
    }
}

// Round 7
// 190.216 us; speedup vs baseline: 1.1999x; 1.0119x over previous
//
#include <hip/hip_runtime.h>

#define H 1024
#define HH (H * H)
#define BATCH 8192
#define NSTEPS 50

typedef __attribute__((ext_vector_type(8))) short bf16x8;
typedef __attribute__((ext_vector_type(4))) float f32x4;

// ---------------------------------------------------------------------------
// helpers
// ---------------------------------------------------------------------------
__device__ __forceinline__ void split2(float a, unsigned short& h, unsigned short& l)
{
    unsigned u = __float_as_uint(a);
    float r = a - __uint_as_float(u & 0xFFFF0000u);   // exact residual
    h = (unsigned short)(u >> 16);                    // truncated bf16
    l = (unsigned short)((__float_as_uint(r) + 0x8000u) >> 16); // rounded residual
}
__device__ __forceinline__ float bf2f(unsigned short s)
{
    return __uint_as_float(((unsigned)s) << 16);
}
__device__ __forceinline__ void gload16(const void* g, void* l)
{
    __builtin_amdgcn_global_load_lds(
        (const __attribute__((address_space(1))) void*)g,
        (__attribute__((address_space(3))) void*)l, 16, 0, 0);
}
#define VMCNT(n) asm volatile("s_waitcnt vmcnt(" #n ")" ::: "memory")
#define RBAR() do { __builtin_amdgcn_s_barrier(); __builtin_amdgcn_sched_barrier(0); } while (0)

// ---------------------------------------------------------------------------
// build A = I + h*W as bf16 hi/lo planes; c = h*b (fp32, also v0)
// ---------------------------------------------------------------------------
__global__ void build_k(unsigned short* __restrict__ Ahi, unsigned short* __restrict__ Alo,
                        const float* __restrict__ W,
                        const float* __restrict__ t0, const float* __restrict__ t1)
{
    const float h = (t1[0] - t0[0]) / (float)NSTEPS;
    const int i4 = blockIdx.x * 256 + threadIdx.x;   // float4 index
    const int idx = i4 * 4;
    const int r = idx >> 10;
    const int cb = idx & 1023;
    const float4 w = ((const float4*)W)[i4];
    float a[4] = {h * w.x, h * w.y, h * w.z, h * w.w};
    #pragma unroll
    for (int j = 0; j < 4; ++j)
        if (cb + j == r) a[j] += 1.0f;
    ushort4 hv, lv;
    split2(a[0], hv.x, lv.x);
    split2(a[1], hv.y, lv.y);
    split2(a[2], hv.z, lv.z);
    split2(a[3], hv.w, lv.w);
    ((ushort4*)Ahi)[i4] = hv;
    ((ushort4*)Alo)[i4] = lv;
}

__global__ void build_c_k(float* __restrict__ cvec, float* __restrict__ v0,
                          const float* __restrict__ b,
                          const float* __restrict__ t0, const float* __restrict__ t1)
{
    const float h = (t1[0] - t0[0]) / (float)NSTEPS;
    const int i = blockIdx.x * 256 + threadIdx.x;
    const float v = h * b[i];
    cvec[i] = v;
    v0[i] = v;
}

// ---------------------------------------------------------------------------
// transpose a pair of bf16 planes (1024x1024): D = S^T
// ---------------------------------------------------------------------------
__global__ void transpose_pair_k(const unsigned short* __restrict__ Shi,
                                 const unsigned short* __restrict__ Slo,
                                 unsigned short* __restrict__ Dhi,
                                 unsigned short* __restrict__ Dlo)
{
    __shared__ unsigned short th[64][68], tl[64][68];
    const int t = threadIdx.x;
    const int cb = blockIdx.x * 64;  // src col base
    const int rb = blockIdx.y * 64;  // src row base
    #pragma unroll
    for (int p = 0; p < 4; ++p) {
        const int row = p * 16 + (t >> 4);
        const int c4 = (t & 15) * 4;
        *(ushort4*)&th[row][c4] = *(const ushort4*)&Shi[(size_t)(rb + row) * H + cb + c4];
        *(ushort4*)&tl[row][c4] = *(const ushort4*)&Slo[(size_t)(rb + row) * H + cb + c4];
    }
    __syncthreads();
    #pragma unroll
    for (int p = 0; p < 4; ++p) {
        const int row = p * 16 + (t >> 4);      // dst row = src col
        const int c4 = (t & 15) * 4;            // dst col = src row
        ushort4 hv, lv;
        hv.x = th[c4 + 0][row]; hv.y = th[c4 + 1][row];
        hv.z = th[c4 + 2][row]; hv.w = th[c4 + 3][row];
        lv.x = tl[c4 + 0][row]; lv.y = tl[c4 + 1][row];
        lv.z = tl[c4 + 2][row]; lv.w = tl[c4 + 3][row];
        *(ushort4*)&Dhi[(size_t)(cb + row) * H + rb + c4] = hv;
        *(ushort4*)&Dlo[(size_t)(cb + row) * H + rb + c4] = lv;
    }
}

// ---------------------------------------------------------------------------
// fused chain step (round-4 structure, 3-product MFMA): 272 blocks x 512 thr.
//  blocks [0,256):  Q = L * R  (64x64 tile, 8 waves, in-block split-K=2,
//                   2-buffer __syncthreads staging via gload_lds)
//  blocks [256,272): vout = addv + (Lhi+Llo) * vin
// XCD assignment: 2D patch (4 m-tiles x 8 n-tiles per XCD) -> per-XCD operand
// working set = 3MB (L2-resident), instead of 8.5MB with 1D slicing.
// ---------------------------------------------------------------------------
template<bool WRITE_T>
__launch_bounds__(512)
__global__ void chain_fused_k(const unsigned short* __restrict__ Lhi,
                              const unsigned short* __restrict__ Llo,
                              const unsigned short* __restrict__ RThi,
                              const unsigned short* __restrict__ RTlo,
                              unsigned short* __restrict__ Qhi,
                              unsigned short* __restrict__ Qlo,
                              unsigned short* __restrict__ QhiT,
                              unsigned short* __restrict__ QloT,
                              const float* __restrict__ vin,
                              const float* __restrict__ addv,
                              float* __restrict__ vout)
{
    __shared__ unsigned short sA[2][2][2][64][32];  // [dbuf][khalf][plane][row][k] 32KB
    __shared__ unsigned short sB[2][2][2][64][32];  // 32KB

    const int tid = threadIdx.x;
    const int bid = blockIdx.x;
    const int wave = tid >> 6, lane = tid & 63;

    if (bid >= 256) {
        // ---- matvec blocks ----
        const int rowbase = (bid - 256) * 64 + wave * 8;
        const float4* xq = (const float4*)vin + lane * 4;
        float4 xv[4];
        #pragma unroll
        for (int q = 0; q < 4; ++q) xv[q] = xq[q];
        #pragma unroll
        for (int rr = 0; rr < 8; ++rr) {
            const int row = rowbase + rr;
            const unsigned short* mh = Lhi + (size_t)row * H + lane * 16;
            const unsigned short* ml = Llo + (size_t)row * H + lane * 16;
            bf16x8 h0 = *(const bf16x8*)&mh[0];
            bf16x8 h1 = *(const bf16x8*)&mh[8];
            bf16x8 l0 = *(const bf16x8*)&ml[0];
            bf16x8 l1 = *(const bf16x8*)&ml[8];
            float s = 0.0f;
            #pragma unroll
            for (int q = 0; q < 8; ++q) {
                const float m0v = bf2f((unsigned short)h0[q]) + bf2f((unsigned short)l0[q]);
                const float m1v = bf2f((unsigned short)h1[q]) + bf2f((unsigned short)l1[q]);
                const float* xf = (const float*)xv;
                s = fmaf(m0v, xf[q], s);
                s = fmaf(m1v, xf[8 + q], s);
            }
            #pragma unroll
            for (int off = 32; off; off >>= 1)
                s += __shfl_down(s, off, 64);
            if (lane == 0) vout[row] = addv[row] + s;
        }
        return;
    }

    // ---- GEMM blocks ----
    const int lg = lane >> 4, lm = lane & 15;
    const int half = wave >> 2;               // k-half owner
    const int wq = wave & 3;
    const int wr2 = (wq >> 1) * 32, wc2 = (wq & 1) * 32;
    // 2D patch per XCD: XCD x -> m-tiles [4*(x>>1), +4), n-tiles [8*(x&1), +8)
    const int xcd = bid & 7;
    const int idx0 = bid >> 3;                 // 0..31 within patch
    const int mt = (xcd >> 1) * 4 + (idx0 & 3);
    const int nt = (xcd & 1) * 8 + (idx0 >> 2);
    const int m0 = mt * 64, n0 = nt * 64;

    f32x4 acc[2][2] = {};

    #define CSTAGE(tt, b) do {                                                   \
        _Pragma("unroll")                                                        \
        for (int it = 0; it < 4; ++it) {                                         \
            const int idx = tid + it * 512;                                      \
            const int mat = idx >> 10, kh = (idx >> 9) & 1;                      \
            const int plane = (idx >> 8) & 1;                                    \
            const int row = (idx >> 2) & 63, kc = idx & 3;                       \
            const int ks = kc ^ ((row >> 1) & 3);                                \
            const unsigned short* g = mat ? (plane ? RTlo : RThi)                \
                                          : (plane ? Llo : Lhi);                 \
            const int rb = mat ? n0 : m0;                                        \
            unsigned short* d = mat ? &sB[b][kh][plane][row][kc * 8]             \
                                    : &sA[b][kh][plane][row][kc * 8];            \
            gload16(g + (size_t)(rb + row) * H + kh * 512 + (tt) * 32 + ks * 8, d); \
        }                                                                        \
    } while (0)

    CSTAGE(0, 0);
    __syncthreads();
    int buf = 0;
    for (int t = 0; t < 16; ++t) {
        if (t + 1 < 16) CSTAGE(t + 1, buf ^ 1);
        bf16x8 ah[2], al[2], bh[2], bl[2];
        #pragma unroll
        for (int i = 0; i < 2; ++i) {
            const int row = wr2 + i * 16 + lm;
            const int sl = lg ^ ((row >> 1) & 3);
            ah[i] = *(const bf16x8*)&sA[buf][half][0][row][sl * 8];
            al[i] = *(const bf16x8*)&sA[buf][half][1][row][sl * 8];
            const int rn = wc2 + i * 16 + lm;
            const int sn = lg ^ ((rn >> 1) & 3);
            bh[i] = *(const bf16x8*)&sB[buf][half][0][rn][sn * 8];
            bl[i] = *(const bf16x8*)&sB[buf][half][1][rn][sn * 8];
        }
        #pragma unroll
        for (int i = 0; i < 2; ++i)
            #pragma unroll
            for (int j = 0; j < 2; ++j) {
                acc[i][j] = __builtin_amdgcn_mfma_f32_16x16x32_bf16(ah[i], bh[j], acc[i][j], 0, 0, 0);
                acc[i][j] = __builtin_amdgcn_mfma_f32_16x16x32_bf16(ah[i], bl[j], acc[i][j], 0, 0, 0);
                acc[i][j] = __builtin_amdgcn_mfma_f32_16x16x32_bf16(al[i], bh[j], acc[i][j], 0, 0, 0);
            }
        __syncthreads();
        buf ^= 1;
    }
    #undef CSTAGE

    // cross-half reduce via LDS (stride 17 floats)
    float* red = (float*)&sA[0][0][0][0][0];
    const int ridx = wq * 64 + lane;
    if (half == 1) {
        float* dst = red + (size_t)ridx * 17;
        #pragma unroll
        for (int i = 0; i < 2; ++i)
            #pragma unroll
            for (int j = 0; j < 2; ++j)
                *(f32x4*)&dst[(i * 2 + j) * 4] = acc[i][j];
    }
    __syncthreads();
    if (half == 0) {
        const float* src = red + (size_t)ridx * 17;
        #pragma unroll
        for (int i = 0; i < 2; ++i)
            #pragma unroll
            for (int j = 0; j < 2; ++j) {
                const f32x4 p = *(const f32x4*)&src[(i * 2 + j) * 4];
                acc[i][j] += p;
            }
        #pragma unroll
        for (int i = 0; i < 2; ++i) {
            const int row0 = m0 + wr2 + i * 16 + lg * 4;
            #pragma unroll
            for (int j = 0; j < 2; ++j) {
                const int col = n0 + wc2 + j * 16 + lm;
                unsigned short hs[4], ls[4];
                #pragma unroll
                for (int r = 0; r < 4; ++r) {
                    split2(acc[i][j][r], hs[r], ls[r]);
                    Qhi[(size_t)(row0 + r) * H + col] = hs[r];
                    Qlo[(size_t)(row0 + r) * H + col] = ls[r];
                }
                if (WRITE_T) {
                    ushort4 th, tl;
                    th.x = hs[0]; th.y = hs[1]; th.z = hs[2]; th.w = hs[3];
                    tl.x = ls[0]; tl.y = ls[1]; tl.z = ls[2]; tl.w = ls[3];
                    *(ushort4*)&QhiT[(size_t)col * H + row0] = th;
                    *(ushort4*)&QloT[(size_t)col * H + row0] = tl;
                }
            }
        }
    }
}

// ---------------------------------------------------------------------------
// X [1024][8192] fp32 -> transposed bf16 planes XT [8192][1024] (hi/lo)
// ---------------------------------------------------------------------------
__global__ void transpose_split_X_k(const float* __restrict__ X,
                                    unsigned short* __restrict__ XhiT,
                                    unsigned short* __restrict__ XloT)
{
    __shared__ float ts[64][65];
    const int t = threadIdx.x;
    const int n0 = blockIdx.x * 64;   // batch base
    const int k0 = blockIdx.y * 64;   // k base
    #pragma unroll
    for (int p = 0; p < 4; ++p) {
        const int row = p * 16 + (t >> 4);       // k-local
        const int c4 = (t & 15) * 4;             // n-local
        const float4 v = *(const float4*)&X[(size_t)(k0 + row) * BATCH + n0 + c4];
        ts[row][c4 + 0] = v.x; ts[row][c4 + 1] = v.y;
        ts[row][c4 + 2] = v.z; ts[row][c4 + 3] = v.w;
    }
    __syncthreads();
    #pragma unroll
    for (int p = 0; p < 2; ++p) {
        const int n = p * 32 + (t >> 3);         // n-local
        const int kc = (t & 7) * 8;              // k-local chunk
        bf16x8 hv, lv;
        #pragma unroll
        for (int q = 0; q < 8; ++q) {
            unsigned short hh, ll;
            split2(ts[kc + q][n], hh, ll);
            hv[q] = (short)hh;
            lv[q] = (short)ll;
        }
        *(bf16x8*)&XhiT[(size_t)(n0 + n) * H + k0 + kc] = hv;
        *(bf16x8*)&XloT[(size_t)(n0 + n) * H + k0 + kc] = lv;
    }
}

// ---------------------------------------------------------------------------
// big GEMM, pipelined: C = P * X + bias. 128x128 tile, 8 waves (32x64 each),
// BK=32, 4-buffer counted-vmcnt pipe (stage-ahead-3, vmcnt(8)),
// all operands pre-split bf16 planes.
// XCD swizzle: n-slice per XCD (XT slice 4MB = L2-resident), m-inner order.
// ---------------------------------------------------------------------------
__launch_bounds__(512)
__global__ void big_gemm_pipe_k(const unsigned short* __restrict__ Phi,
                                const unsigned short* __restrict__ Plo,
                                const unsigned short* __restrict__ XhiT,
                                const unsigned short* __restrict__ XloT,
                                float* __restrict__ C, const float* __restrict__ bias)
{
    __shared__ unsigned short sA[4][2][128][32];   // [buf][plane][row][k] 64KB
    __shared__ unsigned short sB[4][2][128][32];   // 64KB

    const int tid = threadIdx.x;
    const int wave = tid >> 6, lane = tid & 63;
    const int lg = lane >> 4, lm = lane & 15;
    const int wr2 = (wave & 3) * 32;     // m offset of wave tile (32 rows)
    const int wc2 = (wave >> 2) * 64;    // n offset of wave tile (64 cols)
    const int bid = blockIdx.x;
    // XCD x (bid&7) owns n-tiles [8x, 8x+8); m varies fastest within the XCD.
    const int l = bid >> 3;
    const int m0 = (l & 7) * 128;
    const int n0 = ((bid & 7) * 8 + (l >> 3)) * 128;

    f32x4 acc[2][4] = {};

    #define BSTAGE(tt, b) do {                                                   \
        _Pragma("unroll")                                                        \
        for (int it = 0; it < 4; ++it) {                                         \
            const int idx = tid + it * 512;                                      \
            const int mat = idx >> 10, plane = (idx >> 9) & 1;                   \
            const int row = (idx >> 2) & 127, kc = idx & 3;                      \
            const int ks = kc ^ ((row >> 1) & 3);                                \
            const unsigned short* g = mat ? (plane ? XloT : XhiT)                \
                                          : (plane ? Plo : Phi);                 \
            const int rb = mat ? n0 : m0;                                        \
            unsigned short* d = mat ? &sB[b][plane][row][kc * 8]                 \
                                    : &sA[b][plane][row][kc * 8];                \
            gload16(g + (size_t)(rb + row) * H + (tt) * 32 + ks * 8, d);         \
        }                                                                        \
    } while (0)

    BSTAGE(0, 0);
    BSTAGE(1, 1);
    BSTAGE(2, 2);
    VMCNT(8);          // 12 outstanding -> forces stage 0 complete
    RBAR();

    #pragma unroll
    for (int t = 0; t < 32; ++t) {
        const int b = t & 3;
        bf16x8 ah[2], al[2], bh[4], bl[4];
        #pragma unroll
        for (int i = 0; i < 2; ++i) {
            const int row = wr2 + i * 16 + lm;
            const int sl = lg ^ ((row >> 1) & 3);
            ah[i] = *(const bf16x8*)&sA[b][0][row][sl * 8];
            al[i] = *(const bf16x8*)&sA[b][1][row][sl * 8];
        }
        #pragma unroll
        for (int j = 0; j < 4; ++j) {
            const int rn = wc2 + j * 16 + lm;
            const int sn = lg ^ ((rn >> 1) & 3);
            bh[j] = *(const bf16x8*)&sB[b][0][rn][sn * 8];
            bl[j] = *(const bf16x8*)&sB[b][1][rn][sn * 8];
        }
        if (t + 3 < 32) BSTAGE(t + 3, (t + 3) & 3);
        __builtin_amdgcn_s_setprio(1);
        #pragma unroll
        for (int i = 0; i < 2; ++i)
            #pragma unroll
            for (int j = 0; j < 4; ++j) {
                acc[i][j] = __builtin_amdgcn_mfma_f32_16x16x32_bf16(ah[i], bh[j], acc[i][j], 0, 0, 0);
                acc[i][j] = __builtin_amdgcn_mfma_f32_16x16x32_bf16(ah[i], bl[j], acc[i][j], 0, 0, 0);
                acc[i][j] = __builtin_amdgcn_mfma_f32_16x16x32_bf16(al[i], bh[j], acc[i][j], 0, 0, 0);
            }
        __builtin_amdgcn_s_setprio(0);
        // end of iter t: ensure stage(t+1) is complete before next iter reads it.
        if (t < 29) VMCNT(8);        // stages t+2, t+3 may remain in flight
        else if (t == 29) VMCNT(4);  // stage 31 may remain
        else if (t == 30) VMCNT(0);
        if (t < 31) RBAR();
    }
    #undef BSTAGE

    #pragma unroll
    for (int i = 0; i < 2; ++i) {
        const int row0 = m0 + wr2 + i * 16 + lg * 4;
        #pragma unroll
        for (int r = 0; r < 4; ++r) {
            const float bv = bias[row0 + r];
            float* dst = &C[(size_t)(row0 + r) * BATCH + n0 + wc2 + lm];
            #pragma unroll
            for (int j = 0; j < 4; ++j)
                dst[j * 16] = acc[i][j][r] + bv;
        }
    }
}

// ---------------------------------------------------------------------------
// big GEMM fallback (X split in-kernel) — known-good ~70us path
// ---------------------------------------------------------------------------
#define PADK 40

__launch_bounds__(256)
__global__ void big_gemm_k(const unsigned short* __restrict__ Ahi_g,
                           const unsigned short* __restrict__ Alo_g,
                           const float* __restrict__ X, float* __restrict__ C,
                           const float* __restrict__ bias)
{
    __shared__ unsigned short Ahi[128][PADK], Alo[128][PADK];
    __shared__ unsigned short Bhi[128][PADK], Blo[128][PADK];

    const int tid = threadIdx.x;
    const int wave = tid >> 6;
    const int lane = tid & 63;
    const int wr = (wave >> 1) * 64;
    const int wc = (wave & 1) * 64;
    const int m0 = blockIdx.y * 128;
    const int n0 = blockIdx.x * 128;
    const int lg = lane >> 4;
    const int lm = lane & 15;

    f32x4 acc[4][4] = {};

    for (int k0 = 0; k0 < H; k0 += 32) {
        #pragma unroll
        for (int a2 = 0; a2 < 2; ++a2) {
            const int id = tid + a2 * 256;
            const int row = id >> 2;
            const int ko = id & 3;
            const size_t g = (size_t)(m0 + row) * H + k0 + ko * 8;
            *(bf16x8*)&Ahi[row][ko * 8] = *(const bf16x8*)&Ahi_g[g];
            *(bf16x8*)&Alo[row][ko * 8] = *(const bf16x8*)&Alo_g[g];
        }
        #pragma unroll
        for (int a2 = 0; a2 < 2; ++a2) {
            const int id = tid + a2 * 256;
            const int n = id & 127;
            const int ko = id >> 7;
            const float* src = &X[(size_t)(k0 + ko * 8) * BATCH + n0 + n];
            bf16x8 bh, bl;
            #pragma unroll
            for (int i = 0; i < 8; ++i) {
                unsigned short hh, ll;
                split2(src[(size_t)i * BATCH], hh, ll);
                bh[i] = (short)hh;
                bl[i] = (short)ll;
            }
            *(bf16x8*)&Bhi[n][ko * 8] = bh;
            *(bf16x8*)&Blo[n][ko * 8] = bl;
        }
        __syncthreads();

        bf16x8 ah[4], al[4], bh[4], bl[4];
        #pragma unroll
        for (int i = 0; i < 4; ++i) {
            const int m = wr + i * 16 + lm;
            ah[i] = *(const bf16x8*)&Ahi[m][lg * 8];
            al[i] = *(const bf16x8*)&Alo[m][lg * 8];
            const int n = wc + i * 16 + lm;
            bh[i] = *(const bf16x8*)&Bhi[n][lg * 8];
            bl[i] = *(const bf16x8*)&Blo[n][lg * 8];
        }
        #pragma unroll
        for (int i = 0; i < 4; ++i)
            #pragma unroll
            for (int j = 0; j < 4; ++j) {
                acc[i][j] = __builtin_amdgcn_mfma_f32_16x16x32_bf16(ah[i], bh[j], acc[i][j], 0, 0, 0);
                acc[i][j] = __builtin_amdgcn_mfma_f32_16x16x32_bf16(ah[i], bl[j], acc[i][j], 0, 0, 0);
                acc[i][j] = __builtin_amdgcn_mfma_f32_16x16x32_bf16(al[i], bh[j], acc[i][j], 0, 0, 0);
            }
        __syncthreads();
    }

    #pragma unroll
    for (int i = 0; i < 4; ++i) {
        const int rowb = m0 + wr + i * 16 + lg * 4;
        #pragma unroll
        for (int r = 0; r < 4; ++r) {
            const float bv = bias[rowb + r];
            float* dst = &C[(size_t)(rowb + r) * BATCH + n0 + wc + lm];
            #pragma unroll
            for (int j = 0; j < 4; ++j)
                dst[j * 16] = acc[i][j][r] + bv;
        }
    }
}

// ---------------------------------------------------------------------------
// host-side launcher
// ---------------------------------------------------------------------------
extern "C" void kernel_launch(void* const* d_in, const int* in_sizes, int n_in,
                              void* d_out, int out_size, void* d_ws, size_t ws_size,
                              hipStream_t stream)
{
    const float* x0 = (const float*)d_in[0];
    const float* t0 = (const float*)d_in[1];
    const float* t1 = (const float*)d_in[2];
    const float* W  = (const float*)d_in[3];
    const float* bb = (const float*)d_in[4];
    float* out = (float*)d_out;

    // ws layout: A planes {hi,lo,hiT,loT} (8MB) | cv,v0,v1 | @16MB: XT planes (32MB)
    unsigned short* Ahi  = (unsigned short*)d_ws;
    unsigned short* Alo  = Ahi + HH;
    unsigned short* AhiT = Alo + HH;
    unsigned short* AloT = AhiT + HH;
    float* cv = (float*)(AloT + HH);
    float* v0 = cv + H;
    float* v1 = v0 + H;

    const size_t xtoff = (size_t)16 * 1024 * 1024;
    const bool useXT = ws_size >= xtoff + (size_t)2 * BATCH * H * sizeof(unsigned short);
    unsigned short* XhiT = (unsigned short*)((char*)d_ws + xtoff);
    unsigned short* XloT = XhiT + (size_t)BATCH * H;

    // d_out scratch: two ping-pong plane-sets {hi,lo,hiT,loT}, 8MB each (16MB),
    // fully overwritten by the final 32MB C write.
    unsigned short* PA = (unsigned short*)d_out;
    unsigned short* PB = PA + (size_t)4 * HH;

    build_k<<<HH / 1024, 256, 0, stream>>>(Ahi, Alo, W, t0, t1);
    build_c_k<<<H / 256, 256, 0, stream>>>(cv, v0, bb, t0, t1);
    transpose_pair_k<<<dim3(16, 16), 256, 0, stream>>>(Ahi, Alo, AhiT, AloT);

    // addition chain 1 -> 2 -> 3 -> 6 -> 12 -> 24 -> 25 -> 50
    const int seq[7] = {0, 1, 0, 0, 0, 1, 0};   // 0=SQ, 1=MUL
    unsigned short* cur = Ahi;                  // P_1 = A (4 consecutive planes)
    float* vin = v0;
    float* vout = v1;
    for (int s = 0; s < 7; ++s) {
        const unsigned short* L  = seq[s] ? Ahi : cur;
        const unsigned short* Ll = seq[s] ? Alo : cur + HH;
        const float* addv = seq[s] ? cv : vin;
        if (s < 6) {
            unsigned short* nxt = (s & 1) ? PB : PA;
            chain_fused_k<true><<<272, 512, 0, stream>>>(
                L, Ll, cur + 2 * HH, cur + 3 * HH,
                nxt, nxt + HH, nxt + 2 * HH, nxt + 3 * HH,
                vin, addv, vout);
            cur = nxt;
        } else {
            chain_fused_k<false><<<272, 512, 0, stream>>>(
                L, Ll, cur + 2 * HH, cur + 3 * HH,
                Ahi, Alo, nullptr, nullptr,
                vin, addv, vout);
            cur = Ahi;
        }
        float* tv = vin; vin = vout; vout = tv;
    }
    // cur = P_50 planes (in ws); vin = v_50

    if (useXT) {
        transpose_split_X_k<<<dim3(BATCH / 64, H / 64), 256, 0, stream>>>(x0, XhiT, XloT);
        big_gemm_pipe_k<<<512, 512, 0, stream>>>(Ahi, Alo, XhiT, XloT, out, vin);
    } else {
        big_gemm_k<<<dim3(BATCH / 128, H / 128), 256, 0, stream>>>(
            Ahi, Alo, x0, out, vin);
    }
}